// Round 4
// baseline (315.980 us; speedup 1.0000x reference)
//
#include <hip/hip_runtime.h>
#include <hip/hip_bf16.h>
#include <stdint.h>

// B=8, N=2048, E=1024, H=16, D=64 -> M = B*N = 16384.
// qkv row layout per token: [3][H=16][D=64] = 3072 elems (6144 B)

typedef __attribute__((ext_vector_type(8))) short short8;
typedef __attribute__((ext_vector_type(8))) unsigned short ushort8;
typedef __attribute__((ext_vector_type(4))) float floatx4;

__device__ __forceinline__ unsigned short f2bf(float f) {
  union { float f; uint32_t u; } x; x.f = f;
  uint32_t u = x.u;
  return (unsigned short)((u + 0x7fffu + ((u >> 16) & 1u)) >> 16);  // RNE
}
__device__ __forceinline__ float bf2f(unsigned short s) {
  union { uint32_t u; float f; } x; x.u = ((uint32_t)s) << 16; return x.f;
}
__device__ __forceinline__ void unpack8(uint4 u, float* f) {
  f[0] = bf2f((unsigned short)(u.x & 0xffffu)); f[1] = bf2f((unsigned short)(u.x >> 16));
  f[2] = bf2f((unsigned short)(u.y & 0xffffu)); f[3] = bf2f((unsigned short)(u.y >> 16));
  f[4] = bf2f((unsigned short)(u.z & 0xffffu)); f[5] = bf2f((unsigned short)(u.z >> 16));
  f[6] = bf2f((unsigned short)(u.w & 0xffffu)); f[7] = bf2f((unsigned short)(u.w >> 16));
}

// ---------------- fused fp32 -> bf16 cast ----------------
__global__ __launch_bounds__(256) void cvt_all(const float* __restrict__ x,
                                               const float* __restrict__ w1,
                                               const float* __restrict__ w2,
                                               unsigned short* __restrict__ xb,
                                               unsigned short* __restrict__ w1b,
                                               unsigned short* __restrict__ w2b) {
  int i = blockIdx.x * 256 + threadIdx.x;
  const float* src;
  unsigned short* dst;
  if (i < 2097152) {
    src = x; dst = xb;
  } else if (i < 2097152 + 393216) {
    i -= 2097152; src = w1; dst = w1b;
  } else {
    i -= 2490368; src = w2; dst = w2b;
  }
  long base = (long)i * 8;
  const float4* p = (const float4*)(src + base);
  float4 a = p[0], b = p[1];
  ushort8 r;
  r[0] = f2bf(a.x); r[1] = f2bf(a.y); r[2] = f2bf(a.z); r[3] = f2bf(a.w);
  r[4] = f2bf(b.x); r[5] = f2bf(b.y); r[6] = f2bf(b.z); r[7] = f2bf(b.w);
  *(ushort8*)(dst + base) = r;
}

// ---------------- async global->LDS, 16B per lane ----------------
__device__ __forceinline__ void gl2lds16(const void* g, void* l) {
  __builtin_amdgcn_global_load_lds(
      (const uint32_t __attribute__((address_space(1)))*)g,
      (uint32_t __attribute__((address_space(3)))*)(uint32_t)(uintptr_t)l,
      16, 0, 0);
}

// ---------------- bf16 GEMM: C = A*B^T + bias (256x256 tile) ----------------
// 8 waves (2M x 4N), per-wave C = 128x64 via 8x4 frags of mfma_f32_16x16x32_bf16.
// BK=32, 4-deep LDS ring (4x16KB per matrix = 128KB): tile kt in buf(kt&3);
// during window kt we stage tile kt+3 into buf((kt+3)&3) (the buffer freed at
// the end of window kt-1 -> WAR safe with ONE barrier per window).
// Round-4 change: intra-wave software pipeline of ds_read vs MFMA. The 32 MFMA
// are split into 4 clusters of 8 (m-pair x all n); each cluster's A-reads are
// issued one cluster ahead and gated by a counted lgkmcnt(2), so the LDS drain
// (96KB/window/CU, the round-3 serial cost) hides under the previous cluster's
// MFMA burst. Ring + vmcnt ladder identical to the HW-verified round-3 kernel:
//   window-end: vmcnt(8) -> tile kt+1 landed (counted, never 0 mid-loop),
//   one s_barrier per window.
// LDS XOR swizzle (both-sides): chunk ch stored at ch ^ ((row>>1)&3); applied
// on the pre-swizzled GLOBAL source (linear LDS dest) and the ds_read address.
// Grid: 1D with group-of-8-rows mapping so XCD=id%8 pins one A panel per group.
template <bool OUT_BF16>
__device__ __forceinline__ void gemm256_core(const unsigned short* __restrict__ A,
                                             const unsigned short* __restrict__ Bm,
                                             const float* __restrict__ bias,
                                             void* __restrict__ Cout,
                                             int K, int ncols, int ldc) {
  __shared__ __align__(16) char lds[131072];
  char* lA = lds;            // 4 bufs x 16KB
  char* lB = lds + 65536;    // 4 bufs x 16KB

  const int id = blockIdx.x;
  const int local = id % (8 * ncols);
  const int brow = (id / (8 * ncols)) * 8 + (local & 7);
  const int bcol = local >> 3;
  const long row0 = (long)brow * 256;
  const long col0 = (long)bcol * 256;

  const int tid = threadIdx.x;
  const int lane = tid & 63;
  const int wave = tid >> 6;
  const int wm = wave >> 2;   // 0..1 (M half)
  const int wn = wave & 3;    // 0..3 (N quarter)
  const int l15 = lane & 15;
  const int lk = lane >> 4;   // nominal 16B chunk (k-group)

  // Load bias FIRST and drain, so the vmcnt queue holds staging loads only.
  float bv[4];
#pragma unroll
  for (int n = 0; n < 4; ++n) bv[n] = bias[col0 + wn * 64 + n * 16 + l15];
  asm volatile("s_waitcnt vmcnt(0)" ::: "memory");

  // staging: thread t covers LDS row t>>2 (per 128-row round), chunk t&3.
  // global chunk pre-swizzled: gch = (t&3) ^ ((row>>1)&3) = (t&3) ^ ((t>>3)&3)
  const int trow = tid >> 2;
  const int gch = (tid & 3) ^ ((tid >> 3) & 3);
  const unsigned short* gA = A + (row0 + trow) * (long)K + gch * 8;
  const unsigned short* gB = Bm + (col0 + trow) * (long)K + gch * 8;
  const long rstep = (long)128 * K;   // round 1: rows +128
  char* dA = lA + tid * 16;
  char* dB = lB + tid * 16;

  // fragment read offsets (swizzled chunk; (row>>1)&3 == (l15>>1)&3 since all
  // row bases are multiples of 16)
  const int ch = ((lk ^ ((l15 >> 1) & 3)) << 4);
  const int aoff = (wm * 128 + l15) * 64 + ch;   // + m*1024 + buf*16384
  const int boff = (wn * 64 + l15) * 64 + ch;    // + n*1024 + buf*16384

  floatx4 acc[8][4] = {};
  const int NT = K >> 5;   // K-tiles of 32

  // prologue: stage tiles 0,1,2 (4 loads each)
#pragma unroll
  for (int t = 0; t < 3; ++t) {
    const long ko = (long)t * 32;
    gl2lds16(gA + ko, dA + t * 16384);
    gl2lds16(gA + rstep + ko, dA + t * 16384 + 8192);
    gl2lds16(gB + ko, dB + t * 16384);
    gl2lds16(gB + rstep + ko, dB + t * 16384 + 8192);
  }
  asm volatile("s_waitcnt vmcnt(8)" ::: "memory");  // tile 0 landed
  __builtin_amdgcn_s_barrier();

#pragma unroll 1
  for (int kt = 0; kt < NT; ++kt) {
    const char* bufA = lA + (kt & 3) * 16384;
    const char* bufB = lB + (kt & 3) * 16384;
    const bool stage = (kt + 3 < NT);
    const long ko = (long)(kt + 3) * 32;
    const int sb = ((kt + 3) & 3) * 16384;

    short8 af[8], bfr[4];
    // cluster-0 deps: bfr0-3 + af0-1 (6 reads, oldest)
#pragma unroll
    for (int n = 0; n < 4; ++n) bfr[n] = *(const short8*)(bufB + boff + n * 1024);
    af[0] = *(const short8*)(bufA + aoff + 0 * 1024);
    af[1] = *(const short8*)(bufA + aoff + 1 * 1024);
    // cluster-1 reads issued ahead
    af[2] = *(const short8*)(bufA + aoff + 2 * 1024);
    af[3] = *(const short8*)(bufA + aoff + 3 * 1024);
    asm volatile("s_waitcnt lgkmcnt(2)" ::: "memory");   // bfr0-3, af0-1 done
    __builtin_amdgcn_sched_barrier(0);
    __builtin_amdgcn_s_setprio(1);
#pragma unroll
    for (int n = 0; n < 4; ++n) {
      acc[0][n] = __builtin_amdgcn_mfma_f32_16x16x32_bf16(af[0], bfr[n], acc[0][n], 0, 0, 0);
      acc[1][n] = __builtin_amdgcn_mfma_f32_16x16x32_bf16(af[1], bfr[n], acc[1][n], 0, 0, 0);
    }
    __builtin_amdgcn_s_setprio(0);
    // cluster-2 reads issued ahead
    af[4] = *(const short8*)(bufA + aoff + 4 * 1024);
    af[5] = *(const short8*)(bufA + aoff + 5 * 1024);
    asm volatile("s_waitcnt lgkmcnt(2)" ::: "memory");   // af2-3 done
    __builtin_amdgcn_sched_barrier(0);
    __builtin_amdgcn_s_setprio(1);
#pragma unroll
    for (int n = 0; n < 4; ++n) {
      acc[2][n] = __builtin_amdgcn_mfma_f32_16x16x32_bf16(af[2], bfr[n], acc[2][n], 0, 0, 0);
      acc[3][n] = __builtin_amdgcn_mfma_f32_16x16x32_bf16(af[3], bfr[n], acc[3][n], 0, 0, 0);
    }
    __builtin_amdgcn_s_setprio(0);
    // cluster-3 reads + next-tile staging issued ahead
    af[6] = *(const short8*)(bufA + aoff + 6 * 1024);
    af[7] = *(const short8*)(bufA + aoff + 7 * 1024);
    if (stage) {
      gl2lds16(gA + ko, dA + sb);
      gl2lds16(gA + rstep + ko, dA + sb + 8192);
      gl2lds16(gB + ko, dB + sb);
      gl2lds16(gB + rstep + ko, dB + sb + 8192);
    }
    asm volatile("s_waitcnt lgkmcnt(2)" ::: "memory");   // af4-5 done
    __builtin_amdgcn_sched_barrier(0);
    __builtin_amdgcn_s_setprio(1);
#pragma unroll
    for (int n = 0; n < 4; ++n) {
      acc[4][n] = __builtin_amdgcn_mfma_f32_16x16x32_bf16(af[4], bfr[n], acc[4][n], 0, 0, 0);
      acc[5][n] = __builtin_amdgcn_mfma_f32_16x16x32_bf16(af[5], bfr[n], acc[5][n], 0, 0, 0);
    }
    __builtin_amdgcn_s_setprio(0);
    asm volatile("s_waitcnt lgkmcnt(0)" ::: "memory");   // af6-7 done
    __builtin_amdgcn_sched_barrier(0);
    __builtin_amdgcn_s_setprio(1);
#pragma unroll
    for (int n = 0; n < 4; ++n) {
      acc[6][n] = __builtin_amdgcn_mfma_f32_16x16x32_bf16(af[6], bfr[n], acc[6][n], 0, 0, 0);
      acc[7][n] = __builtin_amdgcn_mfma_f32_16x16x32_bf16(af[7], bfr[n], acc[7][n], 0, 0, 0);
    }
    __builtin_amdgcn_s_setprio(0);
    __builtin_amdgcn_sched_barrier(0);
    // window-end counted wait: tile kt+1 must be landed before next window
    if (kt < NT - 3) { asm volatile("s_waitcnt vmcnt(8)" ::: "memory"); }
    else if (kt == NT - 3) { asm volatile("s_waitcnt vmcnt(4)" ::: "memory"); }
    else if (kt == NT - 2) { asm volatile("s_waitcnt vmcnt(0)" ::: "memory"); }
    __builtin_amdgcn_s_barrier();
  }

  // epilogue: C/D layout of 16x16x32: col = lane&15, row = (lane>>4)*4 + reg
  const long crow0 = row0 + wm * 128 + lk * 4;
  const long ccol0 = col0 + wn * 64 + l15;
#pragma unroll
  for (int m = 0; m < 8; ++m)
#pragma unroll
    for (int n = 0; n < 4; ++n)
#pragma unroll
      for (int r = 0; r < 4; ++r) {
        const long row = crow0 + m * 16 + r;
        const long col = ccol0 + n * 16;
        const float v = acc[m][n][r] + bv[n];
        if (OUT_BF16)
          ((unsigned short*)Cout)[row * ldc + col] = f2bf(v);
        else
          ((float*)Cout)[row * ldc + col] = v;
      }
}

__global__ __launch_bounds__(512, 2) void gemm_qkv(const unsigned short* __restrict__ A,
                                                   const unsigned short* __restrict__ Bm,
                                                   const float* __restrict__ bias,
                                                   unsigned short* __restrict__ Cout, int K) {
  gemm256_core<true>(A, Bm, bias, Cout, K, 12, 3072);
}
__global__ __launch_bounds__(512, 2) void gemm_out(const unsigned short* __restrict__ A,
                                                   const unsigned short* __restrict__ Bm,
                                                   const float* __restrict__ bias,
                                                   float* __restrict__ Cout, int K) {
  gemm256_core<false>(A, Bm, bias, Cout, K, 4, 1024);
}

// ---------------- per-token cross-head attention: LDS broadcast ----------------
__global__ __launch_bounds__(256) void attn_kernel(const unsigned short* __restrict__ qkv,
                                                   unsigned short* __restrict__ out2) {
  __shared__ __align__(16) char lds[4 * 6144];  // 24 KB
  const int tid = threadIdx.x;
  const int wave = tid >> 6;
  const int lane = tid & 63;
  const int token = blockIdx.x * 4 + wave;
  const int head = lane >> 2;
  const int sub = lane & 3;
  const int b = token >> 11;
  const int s = token & 2047;

  const char* gbase = (const char*)qkv + (long)token * 6144;
  char* lbase = lds + wave * 6144;
#pragma unroll
  for (int p = 0; p < 6; p++)
    gl2lds16(gbase + p * 1024 + lane * 16, lbase + p * 1024 + lane * 16);
  __syncthreads();

  float qf[16];
  {
    const uint4* qp = (const uint4*)(lbase + head * 128 + sub * 32);
    unpack8(qp[0], qf);
    unpack8(qp[1], qf + 8);
  }

  float e[16];
  const char* kbase = lbase + 2048 + sub * 32;
  for (int j = 0; j < 16; j++) {
    const uint4* kp = (const uint4*)(kbase + j * 128);
    float kf[16];
    unpack8(kp[0], kf);
    unpack8(kp[1], kf + 8);
    float a0 = 0.f, a1 = 0.f, a2 = 0.f, a3 = 0.f;
#pragma unroll
    for (int c = 0; c < 4; c++) {
      a0 += qf[c] * kf[c];
      a1 += qf[c + 4] * kf[c + 4];
      a2 += qf[c + 8] * kf[c + 8];
      a3 += qf[c + 12] * kf[c + 12];
    }
    float ej = (a0 + a1) + (a2 + a3);
    ej += __shfl_xor(ej, 1);
    ej += __shfl_xor(ej, 2);
    e[j] = ej * 0.03125f;  // / sqrt(1024)
  }

  float mx = e[0];
#pragma unroll
  for (int j = 1; j < 16; j++) mx = fmaxf(mx, e[j]);
  float sum = 0.f;
#pragma unroll
  for (int j = 0; j < 16; j++) { e[j] = __expf(e[j] - mx); sum += e[j]; }
  const float inv = 1.f / sum;

  float o[16];
#pragma unroll
  for (int d = 0; d < 16; d++) o[d] = 0.f;
  const char* vbase = lbase + 4096 + sub * 32;
  for (int j = 0; j < 16; j++) {
    const float wgt = e[j] * inv;
    const uint4* vp = (const uint4*)(vbase + j * 128);
    float vf[16];
    unpack8(vp[0], vf);
    unpack8(vp[1], vf + 8);
#pragma unroll
    for (int d = 0; d < 16; d++) o[d] += wgt * vf[d];
  }

  const long row = (long)b * 2048 + head * 128 + (s >> 4);
  unsigned short* op = out2 + row * 1024 + (long)(s & 15) * 64 + sub * 16;
#pragma unroll
  for (int w = 0; w < 2; w++) {
    ushort8 r;
#pragma unroll
    for (int c = 0; c < 8; c++) r[c] = f2bf(o[w * 8 + c]);
    *(ushort8*)(op + w * 8) = r;
  }
}

extern "C" void kernel_launch(void* const* d_in, const int* in_sizes, int n_in,
                              void* d_out, int out_size, void* d_ws, size_t ws_size,
                              hipStream_t stream) {
  const float* x    = (const float*)d_in[0];  // [8,2048,1024]
  const float* Wqkv = (const float*)d_in[1];  // [3072,1024]
  const float* bqkv = (const float*)d_in[2];  // [3072]
  const float* Wo   = (const float*)d_in[3];  // [1024,1024]
  const float* bo   = (const float*)d_in[4];  // [1024]
  float* out = (float*)d_out;                 // [8,2048,1024] fp32

  char* ws = (char*)d_ws;
  unsigned short* x_bf    = (unsigned short*)(ws);              // 32 MB
  unsigned short* wqkv_bf = (unsigned short*)(ws + 33554432);   // 6 MB
  unsigned short* wo_bf   = (unsigned short*)(ws + 39845888);   // 2 MB
  unsigned short* qkv_bf  = (unsigned short*)(ws + 41943040);   // 96 MB
  unsigned short* out2_bf = (unsigned short*)(ws + 142606336);  // 32 MB

  cvt_all<<<10240, 256, 0, stream>>>(x, Wqkv, Wo, x_bf, wqkv_bf, wo_bf);

  // qkv = x @ Wqkv^T + bqkv  (M=16384, N=3072, K=1024): 64 x 12 tiles of 256^2
  gemm_qkv<<<64 * 12, 512, 0, stream>>>(x_bf, wqkv_bf, bqkv, qkv_bf, 1024);

  // one wave per token: 16384 tokens / 4 waves per block
  attn_kernel<<<4096, 256, 0, stream>>>(qkv_bf, out2_bf);

  // out = out2 @ Wo^T + bo  (M=16384, N=1024, K=1024): 64 x 4 tiles of 256^2
  gemm_out<<<64 * 4, 512, 0, stream>>>(out2_bf, wo_bf, bo, out, 1024);
}

// Round 5
// 302.335 us; speedup vs baseline: 1.0451x; 1.0451x over previous
//
#include <hip/hip_runtime.h>
#include <hip/hip_bf16.h>
#include <stdint.h>

// B=8, N=2048, E=1024, H=16, D=64 -> M = B*N = 16384.
// qkv row layout per token: [3][H=16][D=64] = 3072 elems (6144 B)

typedef __attribute__((ext_vector_type(8))) short short8;
typedef __attribute__((ext_vector_type(8))) unsigned short ushort8;
typedef __attribute__((ext_vector_type(4))) unsigned short ushort4v;
typedef __attribute__((ext_vector_type(4))) float floatx4;

__device__ __forceinline__ unsigned short f2bf(float f) {
  union { float f; uint32_t u; } x; x.f = f;
  uint32_t u = x.u;
  return (unsigned short)((u + 0x7fffu + ((u >> 16) & 1u)) >> 16);  // RNE
}

// ---------------- fused fp32 -> bf16 cast ----------------
__global__ __launch_bounds__(256) void cvt_all(const float* __restrict__ x,
                                               const float* __restrict__ w1,
                                               const float* __restrict__ w2,
                                               unsigned short* __restrict__ xb,
                                               unsigned short* __restrict__ w1b,
                                               unsigned short* __restrict__ w2b) {
  int i = blockIdx.x * 256 + threadIdx.x;
  const float* src;
  unsigned short* dst;
  if (i < 2097152) {
    src = x; dst = xb;
  } else if (i < 2097152 + 393216) {
    i -= 2097152; src = w1; dst = w1b;
  } else {
    i -= 2490368; src = w2; dst = w2b;
  }
  long base = (long)i * 8;
  const float4* p = (const float4*)(src + base);
  float4 a = p[0], b = p[1];
  ushort8 r;
  r[0] = f2bf(a.x); r[1] = f2bf(a.y); r[2] = f2bf(a.z); r[3] = f2bf(a.w);
  r[4] = f2bf(b.x); r[5] = f2bf(b.y); r[6] = f2bf(b.z); r[7] = f2bf(b.w);
  *(ushort8*)(dst + base) = r;
}

// ---------------- async global->LDS, 16B per lane ----------------
__device__ __forceinline__ void gl2lds16(const void* g, void* l) {
  __builtin_amdgcn_global_load_lds(
      (const uint32_t __attribute__((address_space(1)))*)g,
      (uint32_t __attribute__((address_space(3)))*)(uint32_t)(uintptr_t)l,
      16, 0, 0);
}

// ---------------- bf16 GEMM: C = A*B^T + bias (256x256 tile) ----------------
// (unchanged from round 4: best measured GEMM so far, 107 us / MfmaUtil 41%)
// 8 waves (2M x 4N), per-wave C = 128x64 via 8x4 frags of mfma_f32_16x16x32_bf16.
// BK=32, 4-deep LDS ring; one barrier per window; counted vmcnt(8) ladder;
// intra-wave cluster pipeline of ds_read vs MFMA; both-sides XOR swizzle.
template <bool OUT_BF16>
__device__ __forceinline__ void gemm256_core(const unsigned short* __restrict__ A,
                                             const unsigned short* __restrict__ Bm,
                                             const float* __restrict__ bias,
                                             void* __restrict__ Cout,
                                             int K, int ncols, int ldc) {
  __shared__ __align__(16) char lds[131072];
  char* lA = lds;            // 4 bufs x 16KB
  char* lB = lds + 65536;    // 4 bufs x 16KB

  const int id = blockIdx.x;
  const int local = id % (8 * ncols);
  const int brow = (id / (8 * ncols)) * 8 + (local & 7);
  const int bcol = local >> 3;
  const long row0 = (long)brow * 256;
  const long col0 = (long)bcol * 256;

  const int tid = threadIdx.x;
  const int lane = tid & 63;
  const int wave = tid >> 6;
  const int wm = wave >> 2;   // 0..1 (M half)
  const int wn = wave & 3;    // 0..3 (N quarter)
  const int l15 = lane & 15;
  const int lk = lane >> 4;   // nominal 16B chunk (k-group)

  // Load bias FIRST and drain, so the vmcnt queue holds staging loads only.
  float bv[4];
#pragma unroll
  for (int n = 0; n < 4; ++n) bv[n] = bias[col0 + wn * 64 + n * 16 + l15];
  asm volatile("s_waitcnt vmcnt(0)" ::: "memory");

  // staging: thread t covers LDS row t>>2 (per 128-row round), chunk t&3.
  // global chunk pre-swizzled: gch = (t&3) ^ ((row>>1)&3) = (t&3) ^ ((t>>3)&3)
  const int trow = tid >> 2;
  const int gch = (tid & 3) ^ ((tid >> 3) & 3);
  const unsigned short* gA = A + (row0 + trow) * (long)K + gch * 8;
  const unsigned short* gB = Bm + (col0 + trow) * (long)K + gch * 8;
  const long rstep = (long)128 * K;   // round 1: rows +128
  char* dA = lA + tid * 16;
  char* dB = lB + tid * 16;

  // fragment read offsets (swizzled chunk)
  const int ch = ((lk ^ ((l15 >> 1) & 3)) << 4);
  const int aoff = (wm * 128 + l15) * 64 + ch;   // + m*1024 + buf*16384
  const int boff = (wn * 64 + l15) * 64 + ch;    // + n*1024 + buf*16384

  floatx4 acc[8][4] = {};
  const int NT = K >> 5;   // K-tiles of 32

  // prologue: stage tiles 0,1,2 (4 loads each)
#pragma unroll
  for (int t = 0; t < 3; ++t) {
    const long ko = (long)t * 32;
    gl2lds16(gA + ko, dA + t * 16384);
    gl2lds16(gA + rstep + ko, dA + t * 16384 + 8192);
    gl2lds16(gB + ko, dB + t * 16384);
    gl2lds16(gB + rstep + ko, dB + t * 16384 + 8192);
  }
  asm volatile("s_waitcnt vmcnt(8)" ::: "memory");  // tile 0 landed
  __builtin_amdgcn_s_barrier();

#pragma unroll 1
  for (int kt = 0; kt < NT; ++kt) {
    const char* bufA = lA + (kt & 3) * 16384;
    const char* bufB = lB + (kt & 3) * 16384;
    const bool stage = (kt + 3 < NT);
    const long ko = (long)(kt + 3) * 32;
    const int sb = ((kt + 3) & 3) * 16384;

    short8 af[8], bfr[4];
    // cluster-0 deps: bfr0-3 + af0-1 (6 reads, oldest)
#pragma unroll
    for (int n = 0; n < 4; ++n) bfr[n] = *(const short8*)(bufB + boff + n * 1024);
    af[0] = *(const short8*)(bufA + aoff + 0 * 1024);
    af[1] = *(const short8*)(bufA + aoff + 1 * 1024);
    // cluster-1 reads issued ahead
    af[2] = *(const short8*)(bufA + aoff + 2 * 1024);
    af[3] = *(const short8*)(bufA + aoff + 3 * 1024);
    asm volatile("s_waitcnt lgkmcnt(2)" ::: "memory");   // bfr0-3, af0-1 done
    __builtin_amdgcn_sched_barrier(0);
    __builtin_amdgcn_s_setprio(1);
#pragma unroll
    for (int n = 0; n < 4; ++n) {
      acc[0][n] = __builtin_amdgcn_mfma_f32_16x16x32_bf16(af[0], bfr[n], acc[0][n], 0, 0, 0);
      acc[1][n] = __builtin_amdgcn_mfma_f32_16x16x32_bf16(af[1], bfr[n], acc[1][n], 0, 0, 0);
    }
    __builtin_amdgcn_s_setprio(0);
    // cluster-2 reads issued ahead
    af[4] = *(const short8*)(bufA + aoff + 4 * 1024);
    af[5] = *(const short8*)(bufA + aoff + 5 * 1024);
    asm volatile("s_waitcnt lgkmcnt(2)" ::: "memory");   // af2-3 done
    __builtin_amdgcn_sched_barrier(0);
    __builtin_amdgcn_s_setprio(1);
#pragma unroll
    for (int n = 0; n < 4; ++n) {
      acc[2][n] = __builtin_amdgcn_mfma_f32_16x16x32_bf16(af[2], bfr[n], acc[2][n], 0, 0, 0);
      acc[3][n] = __builtin_amdgcn_mfma_f32_16x16x32_bf16(af[3], bfr[n], acc[3][n], 0, 0, 0);
    }
    __builtin_amdgcn_s_setprio(0);
    // cluster-3 reads + next-tile staging issued ahead
    af[6] = *(const short8*)(bufA + aoff + 6 * 1024);
    af[7] = *(const short8*)(bufA + aoff + 7 * 1024);
    if (stage) {
      gl2lds16(gA + ko, dA + sb);
      gl2lds16(gA + rstep + ko, dA + sb + 8192);
      gl2lds16(gB + ko, dB + sb);
      gl2lds16(gB + rstep + ko, dB + sb + 8192);
    }
    asm volatile("s_waitcnt lgkmcnt(2)" ::: "memory");   // af4-5 done
    __builtin_amdgcn_sched_barrier(0);
    __builtin_amdgcn_s_setprio(1);
#pragma unroll
    for (int n = 0; n < 4; ++n) {
      acc[4][n] = __builtin_amdgcn_mfma_f32_16x16x32_bf16(af[4], bfr[n], acc[4][n], 0, 0, 0);
      acc[5][n] = __builtin_amdgcn_mfma_f32_16x16x32_bf16(af[5], bfr[n], acc[5][n], 0, 0, 0);
    }
    __builtin_amdgcn_s_setprio(0);
    asm volatile("s_waitcnt lgkmcnt(0)" ::: "memory");   // af6-7 done
    __builtin_amdgcn_sched_barrier(0);
    __builtin_amdgcn_s_setprio(1);
#pragma unroll
    for (int n = 0; n < 4; ++n) {
      acc[6][n] = __builtin_amdgcn_mfma_f32_16x16x32_bf16(af[6], bfr[n], acc[6][n], 0, 0, 0);
      acc[7][n] = __builtin_amdgcn_mfma_f32_16x16x32_bf16(af[7], bfr[n], acc[7][n], 0, 0, 0);
    }
    __builtin_amdgcn_s_setprio(0);
    __builtin_amdgcn_sched_barrier(0);
    // window-end counted wait: tile kt+1 must be landed before next window
    if (kt < NT - 3) { asm volatile("s_waitcnt vmcnt(8)" ::: "memory"); }
    else if (kt == NT - 3) { asm volatile("s_waitcnt vmcnt(4)" ::: "memory"); }
    else if (kt == NT - 2) { asm volatile("s_waitcnt vmcnt(0)" ::: "memory"); }
    __builtin_amdgcn_s_barrier();
  }

  // epilogue: C/D layout of 16x16x32: col = lane&15, row = (lane>>4)*4 + reg
  const long crow0 = row0 + wm * 128 + lk * 4;
  const long ccol0 = col0 + wn * 64 + l15;
#pragma unroll
  for (int m = 0; m < 8; ++m)
#pragma unroll
    for (int n = 0; n < 4; ++n)
#pragma unroll
      for (int r = 0; r < 4; ++r) {
        const long row = crow0 + m * 16 + r;
        const long col = ccol0 + n * 16;
        const float v = acc[m][n][r] + bv[n];
        if (OUT_BF16)
          ((unsigned short*)Cout)[row * ldc + col] = f2bf(v);
        else
          ((float*)Cout)[row * ldc + col] = v;
      }
}

__global__ __launch_bounds__(512, 2) void gemm_qkv(const unsigned short* __restrict__ A,
                                                   const unsigned short* __restrict__ Bm,
                                                   const float* __restrict__ bias,
                                                   unsigned short* __restrict__ Cout, int K) {
  gemm256_core<true>(A, Bm, bias, Cout, K, 12, 3072);
}
__global__ __launch_bounds__(512, 2) void gemm_out(const unsigned short* __restrict__ A,
                                                   const unsigned short* __restrict__ Bm,
                                                   const float* __restrict__ bias,
                                                   float* __restrict__ Cout, int K) {
  gemm256_core<false>(A, Bm, bias, Cout, K, 4, 1024);
}

// ---------------- per-token cross-head attention v4: MFMA ----------------
// One wave per token. The per-token op is a 16x16x64 GEMM (energy), a 16-wide
// softmax, and a 16x64x16 GEMM (PV) -- previously ~3000 VALU unpack/FMA ops,
// now 6 MFMA + ~120 VALU. All fragment layouts are the HW-verified
// mfma_f32_16x16x32_bf16 mappings from the GEMM above:
//   A-frag: row=l15, k-octet=lk (lane reads A[row][k 8-chunk], 16B)
//   B-frag: col=l15, k-octet=lk (reads B^T[col][k 8-chunk])
//   D:      col=l15, row=lk*4+reg
// SWAPPED QK^T: eT = K.Q^T via mfma(A=K, B=Q) -> lane holds
// eT[j=lk*4+r][q=l15]; softmax over j = 4 regs + shfl_xor(16,32).
// PV as out^T = V^T.attT: B-operand attT[j][q] -- B-frag element i is
// attT[lk*8+i][l15], i.e. exactly the p-regs of lanes (l15,2lk)/(l15,2lk+1):
// 4 shfls assemble it, no LDS transpose. K is zero-padded 16->32 (lk>=2 lanes
// supply zero A/B fragments). A-operand: V[j][c*16+l15] via 8 u16 LDS reads
// per d-chunk (half-wave). D gives out[d=c*16+lk*4+r][q=l15].
// Q/K/V LDS is XOR-swizzled (chunk ^= row&7, both-sides: pre-swizzled gl2lds
// SOURCE + swizzled reads) to break the 16-way D=128 row-stride conflict.
__global__ __launch_bounds__(256) void attn_kernel(const unsigned short* __restrict__ qkv,
                                                   unsigned short* __restrict__ out2) {
  __shared__ __align__(16) char lds[4 * 6144];  // 24 KB
  const int tid = threadIdx.x;
  const int wave = tid >> 6;
  const int lane = tid & 63;
  const int token = blockIdx.x * 4 + wave;
  const int l15 = lane & 15;
  const int lk = lane >> 4;
  const int b = token >> 11;
  const int s = token & 2047;

  const char* gbase = (const char*)qkv + (long)token * 6144;
  char* lbase = lds + wave * 6144;
#pragma unroll
  for (int p = 0; p < 6; p++) {
    const int o = p * 1024 + lane * 16;          // linear LDS dest offset
    const int row = o >> 7;                      // 128B row within token
    const int chs = ((o >> 4) & 7) ^ (row & 7);  // pre-swizzled source chunk
    const int src = (o & ~127) | (chs << 4);
    gl2lds16(gbase + src, lbase + o);
  }
  __syncthreads();

  // ---- QK^T (swapped): eT[j][q] = sum_d K[j][d] Q[q][d] ----
  const int sw = l15 & 7;
  const char* qrow = lbase + l15 * 128;
  const char* krow = lbase + 2048 + l15 * 128;
  const short8 kf0 = *(const short8*)(krow + ((lk ^ sw) << 4));
  const short8 kf1 = *(const short8*)(krow + (((lk + 4) ^ sw) << 4));
  const short8 qf0 = *(const short8*)(qrow + ((lk ^ sw) << 4));
  const short8 qf1 = *(const short8*)(qrow + (((lk + 4) ^ sw) << 4));
  floatx4 e = {};
  e = __builtin_amdgcn_mfma_f32_16x16x32_bf16(kf0, qf0, e, 0, 0, 0);
  e = __builtin_amdgcn_mfma_f32_16x16x32_bf16(kf1, qf1, e, 0, 0, 0);

  // ---- softmax over j (4 regs + lanes ^16, ^32); q = l15 stays lane-local ----
  float ev[4];
#pragma unroll
  for (int r = 0; r < 4; ++r) ev[r] = e[r] * 0.03125f;  // / sqrt(1024)
  float mx = fmaxf(fmaxf(ev[0], ev[1]), fmaxf(ev[2], ev[3]));
  mx = fmaxf(mx, __shfl_xor(mx, 16));
  mx = fmaxf(mx, __shfl_xor(mx, 32));
  float sum = 0.f;
#pragma unroll
  for (int r = 0; r < 4; ++r) { ev[r] = __expf(ev[r] - mx); sum += ev[r]; }
  sum += __shfl_xor(sum, 16);
  sum += __shfl_xor(sum, 32);
  const float inv = 1.f / sum;

  // ---- assemble attT B-frag (j-octet lk from lanes (l15,2lk),(l15,2lk+1)) ----
  const uint32_t pa = (uint32_t)f2bf(ev[0] * inv) | ((uint32_t)f2bf(ev[1] * inv) << 16);
  const uint32_t pb = (uint32_t)f2bf(ev[2] * inv) | ((uint32_t)f2bf(ev[3] * inv) << 16);
  const int src0 = (l15 + 32 * lk) & 63;
  uint32_t w0 = __shfl(pa, src0);
  uint32_t w1 = __shfl(pb, src0);
  uint32_t w2 = __shfl(pa, (src0 + 16) & 63);
  uint32_t w3 = __shfl(pb, (src0 + 16) & 63);
  if (lk >= 2) { w0 = 0; w1 = 0; w2 = 0; w3 = 0; }  // zero-pad K 16->32
  union { short8 s8; uint32_t u[4]; } attf;
  attf.u[0] = w0; attf.u[1] = w1; attf.u[2] = w2; attf.u[3] = w3;

  // ---- PV: out^T[d][q] = sum_j V^T[d][j] attT[j][q], 4 d-chunks of 16 ----
  const long orow = (long)b * 2048 + l15 * 128 + (s >> 4);
  unsigned short* op = out2 + orow * 1024 + (long)(s & 15) * 64;
#pragma unroll
  for (int c = 0; c < 4; ++c) {
    union { short8 s8; unsigned short us[8]; } vf;
    if (lk < 2) {
      const int byte_in = (c * 16 + l15) * 2;    // byte within V row (d dim)
#pragma unroll
      for (int i = 0; i < 8; ++i) {
        const int j = lk * 8 + i;
        const int chv = ((byte_in >> 4) ^ (j & 7));  // V rows are token-rows 32+j
        vf.us[i] = *(const unsigned short*)(lbase + 4096 + j * 128 + (chv << 4) +
                                            (byte_in & 15));
      }
    } else {
#pragma unroll
      for (int i = 0; i < 8; ++i) vf.us[i] = 0;    // zero-pad K 16->32
    }
    floatx4 o = {};
    o = __builtin_amdgcn_mfma_f32_16x16x32_bf16(vf.s8, attf.s8, o, 0, 0, 0);
    // lane: out[d = c*16 + lk*4 + r][head q = l15]
    ushort4v r4;
#pragma unroll
    for (int r = 0; r < 4; ++r) r4[r] = f2bf(o[r]);
    *(ushort4v*)(op + c * 16 + lk * 4) = r4;
  }
}

extern "C" void kernel_launch(void* const* d_in, const int* in_sizes, int n_in,
                              void* d_out, int out_size, void* d_ws, size_t ws_size,
                              hipStream_t stream) {
  const float* x    = (const float*)d_in[0];  // [8,2048,1024]
  const float* Wqkv = (const float*)d_in[1];  // [3072,1024]
  const float* bqkv = (const float*)d_in[2];  // [3072]
  const float* Wo   = (const float*)d_in[3];  // [1024,1024]
  const float* bo   = (const float*)d_in[4];  // [1024]
  float* out = (float*)d_out;                 // [8,2048,1024] fp32

  char* ws = (char*)d_ws;
  unsigned short* x_bf    = (unsigned short*)(ws);              // 32 MB
  unsigned short* wqkv_bf = (unsigned short*)(ws + 33554432);   // 6 MB
  unsigned short* wo_bf   = (unsigned short*)(ws + 39845888);   // 2 MB
  unsigned short* qkv_bf  = (unsigned short*)(ws + 41943040);   // 96 MB
  unsigned short* out2_bf = (unsigned short*)(ws + 142606336);  // 32 MB

  cvt_all<<<10240, 256, 0, stream>>>(x, Wqkv, Wo, x_bf, wqkv_bf, wo_bf);

  // qkv = x @ Wqkv^T + bqkv  (M=16384, N=3072, K=1024): 64 x 12 tiles of 256^2
  gemm_qkv<<<64 * 12, 512, 0, stream>>>(x_bf, wqkv_bf, bqkv, qkv_bf, 1024);

  // one wave per token: 16384 tokens / 4 waves per block
  attn_kernel<<<4096, 256, 0, stream>>>(qkv_bf, out2_bf);

  // out = out2 @ Wo^T + bo  (M=16384, N=1024, K=1024): 64 x 4 tiles of 256^2
  gemm_out<<<64 * 4, 512, 0, stream>>>(out2_bf, wo_bf, bo, out, 1024);
}